// Round 7
// baseline (2460.762 us; speedup 1.0000x reference)
//
#include <hip/hip_runtime.h>
#include <stdint.h>

// Resonator network, b=1024 f=4 v=64 d=2048, 100 iterations.
// All values +-1 -> exact bit arithmetic. Round 7: r6's lean structure
// (1 barrier/iter, period<=2 only, free msim) with the spill killed:
// single always-12-plane phase C (exact: when q<=255 the high ballots are
// zero masks), planes live in SGPRs; manual 8-deep chunked global loads in
// both phases to cover ~200cyc L2 latency (r1/r6 were latency-bound).

#define NB 1024
#define NF 4
#define ND 2048
#define NW 32            // ND/64 words per row
#define ITERS 100

#define OFF_OUT  (NB*NF*ND)
#define OFF_MS   (OFF_OUT + NB*NF)
#define OFF_CONV (OFF_MS + NB*NF)

typedef unsigned long long u64;

// Pack codebooks (f,v,d) +-1 floats into two bit layouts in d_ws:
//  cbB[(j*32+w)*64 + v] : row bits, bit l = sign of cb[j,v,w*64+l]
//  cbT[j*2048 + d]      : column mask, bit v = sign of cb[j,v,d]
__global__ void pack_cb_kernel(const float* __restrict__ cb,
                               u64* __restrict__ cbB, u64* __restrict__ cbT) {
    const int lane = threadIdx.x & 63;
    const int gw   = (blockIdx.x * (blockDim.x >> 6)) + (threadIdx.x >> 6);
    const int nw   = (gridDim.x * blockDim.x) >> 6;
    for (int idx = gw; idx < NF * 64 * NW; idx += nw) {
        const int j = idx >> 11, v = (idx >> 5) & 63, w = idx & 31;
        const float x = cb[(((j << 6) | v) << 11) + (w << 6) + lane];
        const u64 m = __ballot(x < 0.0f);
        if (lane == 0) cbB[(((j << 5) | w) << 6) | v] = m;
    }
    for (int idx = gw; idx < NF * ND; idx += nw) {
        const int j = idx >> 11, d = idx & 2047;
        const float x = cb[(((j << 6) | lane) << 11) + d];
        const u64 m = __ballot(x < 0.0f);
        if (lane == 0) cbT[idx] = m;
    }
}

// phase-C per-word body: t_d = base + cmul*popc(col) + sum_k 2^(k+2)*popc(ck&col)
#define PCWORD(G, W)                                                         \
    {                                                                        \
        int t = base + cmul * (int)__popcll(G);                              \
        t += (int)__popcll(c0  & (G)) << 2;                                  \
        t += (int)__popcll(c1  & (G)) << 3;                                  \
        t += (int)__popcll(c2  & (G)) << 4;                                  \
        t += (int)__popcll(c3  & (G)) << 5;                                  \
        t += (int)__popcll(c4  & (G)) << 6;                                  \
        t += (int)__popcll(c5  & (G)) << 7;                                  \
        t += (int)__popcll(c6  & (G)) << 8;                                  \
        t += (int)__popcll(c7  & (G)) << 9;                                  \
        t += (int)__popcll(c8  & (G)) << 10;                                 \
        t += (int)__popcll(c9  & (G)) << 11;                                 \
        t += (int)__popcll(c10 & (G)) << 12;                                 \
        t += (int)__popcll(c11 & (G)) << 13;                                 \
        const u64 nww = __ballot(t < 0);                                     \
        if (lane == 0) s_hist[nxt][j][W] = nww;                              \
    }

__global__ __launch_bounds__(256, 4) void resonator_kernel(
    const float* __restrict__ inp, const float* __restrict__ est_init,
    const u64* __restrict__ cbB, const u64* __restrict__ cbT,
    float* __restrict__ out) {
    __shared__ u64 s_hist[4][NF][NW];   // est ring (4 slots), 4 KB
    __shared__ u64 s_inp[NW];
    __shared__ u64 s_ne[NF][NW];        // touched only by its own wave
    __shared__ int s_conv[NF];

    const int b    = blockIdx.x;
    const int tid  = threadIdx.x;
    const int j    = tid >> 6;      // wave = factor
    const int lane = tid & 63;

    const u64* cbBj = cbB + (j << 11);
    const u64* cbTj = cbT + (j << 11);

    // ---- pack input (8 words/wave) + est_0 (own factor) ----
    #pragma unroll
    for (int k = 0; k < 8; ++k) {
        const int w = (j << 3) + k;
        const u64 m = __ballot(inp[(b << 11) + (w << 6) + lane] < 0.0f);
        if (lane == 0) s_inp[w] = m;
    }
    #pragma unroll 4
    for (int w = 0; w < NW; ++w) {
        const u64 m = __ballot(
            est_init[(((b << 2) | j) << 11) + (w << 6) + lane] < 0.0f);
        if (lane == 0) s_hist[0][j][w] = m;
    }
    __syncthreads();

    int m_last = 0, m_prev = 0, final_slot = 0;

    for (int it = 0; it < ITERS; ++it) {
        const int cur = it & 3, nxt = (it + 1) & 3, prv = (it + 3) & 3;

        // ne for own factor (own-wave LDS only -> no barrier needed)
        if (lane < NW) {
            const u64 X = s_inp[lane]
                        ^ s_hist[cur][0][lane] ^ s_hist[cur][1][lane]
                        ^ s_hist[cur][2][lane] ^ s_hist[cur][3][lane];
            s_ne[j][lane] = X ^ s_hist[cur][j][lane];
        }

        // ---- phase B: pc_v; lane = v; 8-deep chunked loads ----
        int pc = 0;
        #pragma unroll
        for (int ch = 0; ch < 4; ++ch) {
            const int w8 = ch << 3;
            const u64 g0 = cbBj[((w8 + 0) << 6) | lane];
            const u64 g1 = cbBj[((w8 + 1) << 6) | lane];
            const u64 g2 = cbBj[((w8 + 2) << 6) | lane];
            const u64 g3 = cbBj[((w8 + 3) << 6) | lane];
            const u64 g4 = cbBj[((w8 + 4) << 6) | lane];
            const u64 g5 = cbBj[((w8 + 5) << 6) | lane];
            const u64 g6 = cbBj[((w8 + 6) << 6) | lane];
            const u64 g7 = cbBj[((w8 + 7) << 6) | lane];
            pc += (int)__popcll(s_ne[j][w8 + 0] ^ g0)
                + (int)__popcll(s_ne[j][w8 + 1] ^ g1)
                + (int)__popcll(s_ne[j][w8 + 2] ^ g2)
                + (int)__popcll(s_ne[j][w8 + 3] ^ g3)
                + (int)__popcll(s_ne[j][w8 + 4] ^ g4)
                + (int)__popcll(s_ne[j][w8 + 5] ^ g5)
                + (int)__popcll(s_ne[j][w8 + 6] ^ g6)
                + (int)__popcll(s_ne[j][w8 + 7] ^ g7);
        }

        int mn = pc, spc = pc;
        #pragma unroll
        for (int off = 32; off > 0; off >>= 1) {
            const int a1 = __shfl_xor(mn, off);
            const int a2 = __shfl_xor(spc, off);
            mn = mn < a1 ? mn : a1;
            spc += a2;
        }
        const int q = pc - mn;           // 0..2048, usually <=255
        m_prev = m_last;
        m_last = ND - 2 * mn;            // max_sim of this step, free
        const int base = 131072 - 2 * spc;
        const int cmul = 4 * mn - 4096;
        // 12 exact planes; c8..c11 are zero masks when q<=255 everywhere
        const u64 c0  = __ballot(q & 1),    c1  = __ballot(q & 2);
        const u64 c2  = __ballot(q & 4),    c3  = __ballot(q & 8);
        const u64 c4  = __ballot(q & 16),   c5  = __ballot(q & 32);
        const u64 c6  = __ballot(q & 64),   c7  = __ballot(q & 128);
        const u64 c8  = __ballot(q & 256),  c9  = __ballot(q & 512);
        const u64 c10 = __ballot(q & 1024), c11 = __ballot(q & 2048);

        // ---- phase C: 8-deep chunked loads; lane = d%64 ----
        #pragma unroll
        for (int ch = 0; ch < 4; ++ch) {
            const int w8 = ch << 3;
            const u64 g0 = cbTj[((w8 + 0) << 6) | lane];
            const u64 g1 = cbTj[((w8 + 1) << 6) | lane];
            const u64 g2 = cbTj[((w8 + 2) << 6) | lane];
            const u64 g3 = cbTj[((w8 + 3) << 6) | lane];
            const u64 g4 = cbTj[((w8 + 4) << 6) | lane];
            const u64 g5 = cbTj[((w8 + 5) << 6) | lane];
            const u64 g6 = cbTj[((w8 + 6) << 6) | lane];
            const u64 g7 = cbTj[((w8 + 7) << 6) | lane];
            PCWORD(g0, w8 + 0)
            PCWORD(g1, w8 + 1)
            PCWORD(g2, w8 + 2)
            PCWORD(g3, w8 + 3)
            PCWORD(g4, w8 + 4)
            PCWORD(g5, w8 + 5)
            PCWORD(g6, w8 + 6)
            PCWORD(g7, w8 + 7)
        }

        // ---- period<=2 check: lanes 0-31 compare own factor's words ----
        int df1 = 0, df2 = 0;
        if (lane < NW) {
            const u64 a = s_hist[nxt][j][lane];   // own-wave writes
            df1 = (a != s_hist[cur][j][lane]);
            df2 = (a != s_hist[prv][j][lane]);    // it=0: garbage, guarded below
        }
        const u64 b1 = __ballot(df1), b2 = __ballot(df2);
        if (lane == 0) s_conv[j] = (b1 == 0 ? 1 : 0) | (b2 == 0 ? 2 : 0);
        __syncthreads();                          // the one barrier per iter

        const int fl = s_conv[0] & s_conv[1] & s_conv[2] & s_conv[3];
        final_slot = nxt;
        if (fl & 1) break;                        // fixed point
        if (it >= 1 && (fl & 2)) {                // period-2: resolve by parity
            if (((ITERS - it) & 1) == 0) { final_slot = cur; m_last = m_prev; }
            break;
        }
    }

    // ---- outcome: argmax_v |sim(est_100, cb)|, first-max tie-break ----
    int pcO = 0;
    #pragma unroll
    for (int w = 0; w < NW; ++w)
        pcO += (int)__popcll(s_hist[final_slot][j][w] ^ cbBj[(w << 6) | lane]);
    const int simF = ND - (pcO << 1);
    const int aF   = simF < 0 ? -simF : simF;
    int key = (aF << 6) | (63 - lane);
    #pragma unroll
    for (int off = 32; off > 0; off >>= 1) {
        const int t1 = __shfl_xor(key, off);
        key = key > t1 ? key : t1;
    }
    if (lane == 0) {
        out[OFF_OUT + (b << 2) + j] = (float)(63 - (key & 63));
        out[OFF_MS  + (b << 2) + j] = (float)m_last;
    }

    // ---- unpack est_100 ----
    #pragma unroll 4
    for (int k = 0; k < 32; ++k) {
        const int idx = tid + (k << 8);        // 0..8191
        const int jj = idx >> 11, d = idx & 2047;
        const u64 wrd = s_hist[final_slot][jj][d >> 6];
        out[(b << 13) + idx] = ((wrd >> (d & 63)) & 1) ? -1.0f : 1.0f;
    }
    if (b == 0 && tid == 0) out[OFF_CONV] = 99.0f;
}

extern "C" void kernel_launch(void* const* d_in, const int* in_sizes, int n_in,
                              void* d_out, int out_size, void* d_ws, size_t ws_size,
                              hipStream_t stream) {
    const float* inp  = (const float*)d_in[0];
    const float* est0 = (const float*)d_in[1];
    const float* cb   = (const float*)d_in[2];
    float* out = (float*)d_out;
    u64* cbB = (u64*)d_ws;                 // 8192 words
    u64* cbT = cbB + NF * 64 * NW;         // 8192 words (128 KB of ws total)

    pack_cb_kernel<<<64, 256, 0, stream>>>(cb, cbB, cbT);
    resonator_kernel<<<NB, 256, 0, stream>>>(inp, est0, cbB, cbT, out);
}

// Round 8
// 1742.688 us; speedup vs baseline: 1.4120x; 1.4120x over previous
//
#include <hip/hip_runtime.h>
#include <stdint.h>

// Resonator network, b=1024 f=4 v=64 d=2048, 100 iterations.
// All values +-1 -> exact bit arithmetic. Round 8: r6's lean skeleton
// (4 waves, 1 barrier/iter, period<=2, free msim) with:
//  - __launch_bounds__(256,2): empirical VGPR cap = 256/minwaves on this
//    toolchain; r6/r7's (256,4) capped at 64 regs and spilled ~GBs.
//  - mean-centered 8-plane phase C + exact outlier terms: bulk |pc-mean|
//    fits 8 bits even when converged (min-offset didn't: losers sit at
//    q~1024); strong-match lanes (1-2) handled as exact 4*ex*bit adds,
//    wave-uniform overflow loop for >2 outliers (exact, ~never taken).
//  - chunked loads (B:8-deep, C:4-deep) for L2-latency hiding (r1 issue
//    efficiency was ~33% -> latency-bound).

#define NB 1024
#define NF 4
#define ND 2048
#define NW 32            // ND/64 words per row
#define ITERS 100

#define OFF_OUT  (NB*NF*ND)
#define OFF_MS   (OFF_OUT + NB*NF)
#define OFF_CONV (OFF_MS + NB*NF)

typedef unsigned long long u64;

// Pack codebooks (f,v,d) +-1 floats into two bit layouts in d_ws:
//  cbB[(j*32+w)*64 + v] : row bits, bit l = sign of cb[j,v,w*64+l]
//  cbT[j*2048 + d]      : column mask, bit v = sign of cb[j,v,d]
__global__ void pack_cb_kernel(const float* __restrict__ cb,
                               u64* __restrict__ cbB, u64* __restrict__ cbT) {
    const int lane = threadIdx.x & 63;
    const int gw   = (blockIdx.x * (blockDim.x >> 6)) + (threadIdx.x >> 6);
    const int nw   = (gridDim.x * blockDim.x) >> 6;
    for (int idx = gw; idx < NF * 64 * NW; idx += nw) {
        const int j = idx >> 11, v = (idx >> 5) & 63, w = idx & 31;
        const float x = cb[(((j << 6) | v) << 11) + (w << 6) + lane];
        const u64 m = __ballot(x < 0.0f);
        if (lane == 0) cbB[(((j << 5) | w) << 6) | v] = m;
    }
    for (int idx = gw; idx < NF * ND; idx += nw) {
        const int j = idx >> 11, d = idx & 2047;
        const float x = cb[(((j << 6) | lane) << 11) + d];
        const u64 m = __ballot(x < 0.0f);
        if (lane == 0) cbT[idx] = m;
    }
}

__global__ __launch_bounds__(256, 2) void resonator_kernel(
    const float* __restrict__ inp, const float* __restrict__ est_init,
    const u64* __restrict__ cbB, const u64* __restrict__ cbT,
    float* __restrict__ out) {
    __shared__ u64 s_hist[4][NF][NW];   // est ring (4 slots), 4 KB
    __shared__ u64 s_inp[NW];
    __shared__ u64 s_ne[NF][NW];        // touched only by its own wave
    __shared__ int s_conv[NF];

    const int b    = blockIdx.x;
    const int tid  = threadIdx.x;
    const int j    = tid >> 6;      // wave = factor
    const int lane = tid & 63;

    const u64* cbBj = cbB + (j << 11);
    const u64* cbTj = cbT + (j << 11);

    // ---- pack input (8 words/wave) + est_0 (own factor) ----
    #pragma unroll
    for (int k = 0; k < 8; ++k) {
        const int w = (j << 3) + k;
        const u64 m = __ballot(inp[(b << 11) + (w << 6) + lane] < 0.0f);
        if (lane == 0) s_inp[w] = m;
    }
    #pragma unroll 4
    for (int w = 0; w < NW; ++w) {
        const u64 m = __ballot(
            est_init[(((b << 2) | j) << 11) + (w << 6) + lane] < 0.0f);
        if (lane == 0) s_hist[0][j][w] = m;
    }
    __syncthreads();

    int m_last = 0, m_prev = 0, final_slot = 0;

    for (int it = 0; it < ITERS; ++it) {
        const int cur = it & 3, nxt = (it + 1) & 3, prv = (it + 3) & 3;

        // ne for own factor (own-wave LDS only -> no barrier needed)
        if (lane < NW) {
            const u64 X = s_inp[lane]
                        ^ s_hist[cur][0][lane] ^ s_hist[cur][1][lane]
                        ^ s_hist[cur][2][lane] ^ s_hist[cur][3][lane];
            s_ne[j][lane] = X ^ s_hist[cur][j][lane];
        }

        // ---- phase B: pc_v; lane = v; 8-deep chunked loads ----
        int pc = 0;
        #pragma unroll
        for (int ch = 0; ch < 4; ++ch) {
            const int w8 = ch << 3;
            const u64 g0 = cbBj[((w8 + 0) << 6) | lane];
            const u64 g1 = cbBj[((w8 + 1) << 6) | lane];
            const u64 g2 = cbBj[((w8 + 2) << 6) | lane];
            const u64 g3 = cbBj[((w8 + 3) << 6) | lane];
            const u64 g4 = cbBj[((w8 + 4) << 6) | lane];
            const u64 g5 = cbBj[((w8 + 5) << 6) | lane];
            const u64 g6 = cbBj[((w8 + 6) << 6) | lane];
            const u64 g7 = cbBj[((w8 + 7) << 6) | lane];
            pc += (int)__popcll(s_ne[j][w8 + 0] ^ g0)
                + (int)__popcll(s_ne[j][w8 + 1] ^ g1)
                + (int)__popcll(s_ne[j][w8 + 2] ^ g2)
                + (int)__popcll(s_ne[j][w8 + 3] ^ g3)
                + (int)__popcll(s_ne[j][w8 + 4] ^ g4)
                + (int)__popcll(s_ne[j][w8 + 5] ^ g5)
                + (int)__popcll(s_ne[j][w8 + 6] ^ g6)
                + (int)__popcll(s_ne[j][w8 + 7] ^ g7);
        }

        int mn = pc, spc = pc;
        #pragma unroll
        for (int off = 32; off > 0; off >>= 1) {
            const int a1 = __shfl_xor(mn, off);
            const int a2 = __shfl_xor(spc, off);
            mn = mn < a1 ? mn : a1;
            spc += a2;
        }
        m_prev = m_last;
        m_last = ND - 2 * mn;            // max_sim of this step, free

        // ---- mean-centered exact decomposition ----
        const int mean = spc >> 6;
        const int dev  = pc - mean;
        const int devc = dev < -128 ? -128 : (dev > 127 ? 127 : dev);
        const int ex   = dev - devc;     // nonzero only for strong matches
        const int u    = devc + 128;     // 0..255
        const u64 c0 = __ballot(u & 1),  c1 = __ballot(u & 2);
        const u64 c2 = __ballot(u & 4),  c3 = __ballot(u & 8);
        const u64 c4 = __ballot(u & 16), c5 = __ballot(u & 32);
        const u64 c6 = __ballot(u & 64), c7 = __ballot(u & 128);
        u64 om = __ballot(ex != 0);
        const int nout = (int)__popcll(om);
        int ov0 = 0, ov1 = 0, oe0 = 0, oe1 = 0;
        if (nout > 0) {
            ov0 = __builtin_ctzll(om); om &= om - 1;
            oe0 = 4 * __builtin_amdgcn_readlane(ex, ov0);
            if (nout > 1) {
                ov1 = __builtin_ctzll(om); om &= om - 1;
                oe1 = 4 * __builtin_amdgcn_readlane(ex, ov1);
            }
        }
        // om now holds outliers beyond the first two (essentially never)
        const int base = 131072 - 2 * spc;
        const int cmul = 4 * mean - 4608;

        // ---- phase C: 4-deep chunks; lane = d%64 ----
        // t_d = base + cmul*colb + sum_k 2^(k+2) popc(ck&col) + 4*ex*bit terms
        #pragma unroll
        for (int ch = 0; ch < 8; ++ch) {
            const int w4 = ch << 2;
            const u64 ga = cbTj[((w4 + 0) << 6) | lane];
            const u64 gb = cbTj[((w4 + 1) << 6) | lane];
            const u64 gc = cbTj[((w4 + 2) << 6) | lane];
            const u64 gd = cbTj[((w4 + 3) << 6) | lane];
            #pragma unroll
            for (int k2 = 0; k2 < 4; ++k2) {
                const u64 cw = (k2 == 0) ? ga : (k2 == 1) ? gb
                             : (k2 == 2) ? gc : gd;
                int t = base + cmul * (int)__popcll(cw);
                t += (int)__popcll(c0 & cw) << 2;
                t += (int)__popcll(c1 & cw) << 3;
                t += (int)__popcll(c2 & cw) << 4;
                t += (int)__popcll(c3 & cw) << 5;
                t += (int)__popcll(c4 & cw) << 6;
                t += (int)__popcll(c5 & cw) << 7;
                t += (int)__popcll(c6 & cw) << 8;
                t += (int)__popcll(c7 & cw) << 9;
                t += oe0 * (int)((cw >> ov0) & 1);
                t += oe1 * (int)((cw >> ov1) & 1);
                if (nout > 2) {                    // exact, ~never taken
                    u64 m2 = om;
                    while (m2) {
                        const int vv = __builtin_ctzll(m2); m2 &= m2 - 1;
                        const int ee = 4 * __builtin_amdgcn_readlane(ex, vv);
                        t += ee * (int)((cw >> vv) & 1);
                    }
                }
                const u64 nww = __ballot(t < 0);
                if (lane == 0) s_hist[nxt][j][w4 + k2] = nww;
            }
        }

        // ---- period<=2 check: lanes 0-31 compare own factor's words ----
        int df1 = 0, df2 = 0;
        if (lane < NW) {
            const u64 a = s_hist[nxt][j][lane];   // own-wave writes
            df1 = (a != s_hist[cur][j][lane]);
            df2 = (a != s_hist[prv][j][lane]);    // it=0: garbage, guarded below
        }
        const u64 b1 = __ballot(df1), b2 = __ballot(df2);
        if (lane == 0) s_conv[j] = (b1 == 0 ? 1 : 0) | (b2 == 0 ? 2 : 0);
        __syncthreads();                          // the one barrier per iter

        const int fl = s_conv[0] & s_conv[1] & s_conv[2] & s_conv[3];
        final_slot = nxt;
        if (fl & 1) break;                        // fixed point
        if (it >= 1 && (fl & 2)) {                // period-2: resolve by parity
            if (((ITERS - it) & 1) == 0) { final_slot = cur; m_last = m_prev; }
            break;
        }
    }

    // ---- outcome: argmax_v |sim(est_100, cb)|, first-max tie-break ----
    int pcO = 0;
    #pragma unroll
    for (int w = 0; w < NW; ++w)
        pcO += (int)__popcll(s_hist[final_slot][j][w] ^ cbBj[(w << 6) | lane]);
    const int simF = ND - (pcO << 1);
    const int aF   = simF < 0 ? -simF : simF;
    int key = (aF << 6) | (63 - lane);
    #pragma unroll
    for (int off = 32; off > 0; off >>= 1) {
        const int t1 = __shfl_xor(key, off);
        key = key > t1 ? key : t1;
    }
    if (lane == 0) {
        out[OFF_OUT + (b << 2) + j] = (float)(63 - (key & 63));
        out[OFF_MS  + (b << 2) + j] = (float)m_last;
    }

    // ---- unpack est_100 ----
    #pragma unroll 4
    for (int k = 0; k < 32; ++k) {
        const int idx = tid + (k << 8);        // 0..8191
        const int jj = idx >> 11, d = idx & 2047;
        const u64 wrd = s_hist[final_slot][jj][d >> 6];
        out[(b << 13) + idx] = ((wrd >> (d & 63)) & 1) ? -1.0f : 1.0f;
    }
    if (b == 0 && tid == 0) out[OFF_CONV] = 99.0f;
}

extern "C" void kernel_launch(void* const* d_in, const int* in_sizes, int n_in,
                              void* d_out, int out_size, void* d_ws, size_t ws_size,
                              hipStream_t stream) {
    const float* inp  = (const float*)d_in[0];
    const float* est0 = (const float*)d_in[1];
    const float* cb   = (const float*)d_in[2];
    float* out = (float*)d_out;
    u64* cbB = (u64*)d_ws;                 // 8192 words
    u64* cbT = cbB + NF * 64 * NW;         // 8192 words (128 KB of ws total)

    pack_cb_kernel<<<64, 256, 0, stream>>>(cb, cbB, cbT);
    resonator_kernel<<<NB, 256, 0, stream>>>(inp, est0, cbB, cbT, out);
}

// Round 9
// 1729.833 us; speedup vs baseline: 1.4225x; 1.0074x over previous
//
#include <hip/hip_runtime.h>
#include <stdint.h>

// Resonator network, b=1024 f=4 v=64 d=2048, 100 iterations.
// All values +-1 -> exact bit arithmetic. Round 9: r8's skeleton with TWO
// rows per block: each wave (factor j) runs rows 2b and 2b+1. Codebook
// words are loaded ONCE and used for both rows (2x arithmetic per load ->
// latency converted to issue), and the grid halves to 512 blocks = 2/CU
// = a SINGLE residency round (r8 needed two). Early exit when BOTH rows
// satisfy the exact period<=2 condition at the same iteration (a fixed
// point persists, a 2-cycle keeps alternating -> per-row parity mapping
// at the shared break iteration is exact; r8-validated logic per row).

#define NB 1024
#define NF 4
#define ND 2048
#define NW 32            // ND/64 words per row
#define ITERS 100

#define OFF_OUT  (NB*NF*ND)
#define OFF_MS   (OFF_OUT + NB*NF)
#define OFF_CONV (OFF_MS + NB*NF)

typedef unsigned long long u64;

// Pack codebooks (f,v,d) +-1 floats into two bit layouts in d_ws:
//  cbB[(j*32+w)*64 + v] : row bits, bit l = sign of cb[j,v,w*64+l]
//  cbT[j*2048 + d]      : column mask, bit v = sign of cb[j,v,d]
__global__ void pack_cb_kernel(const float* __restrict__ cb,
                               u64* __restrict__ cbB, u64* __restrict__ cbT) {
    const int lane = threadIdx.x & 63;
    const int gw   = (blockIdx.x * (blockDim.x >> 6)) + (threadIdx.x >> 6);
    const int nw   = (gridDim.x * blockDim.x) >> 6;
    for (int idx = gw; idx < NF * 64 * NW; idx += nw) {
        const int j = idx >> 11, v = (idx >> 5) & 63, w = idx & 31;
        const float x = cb[(((j << 6) | v) << 11) + (w << 6) + lane];
        const u64 m = __ballot(x < 0.0f);
        if (lane == 0) cbB[(((j << 5) | w) << 6) | v] = m;
    }
    for (int idx = gw; idx < NF * ND; idx += nw) {
        const int j = idx >> 11, d = idx & 2047;
        const float x = cb[(((j << 6) | lane) << 11) + d];
        const u64 m = __ballot(x < 0.0f);
        if (lane == 0) cbT[idx] = m;
    }
}

__global__ __launch_bounds__(256, 2) void resonator_kernel(
    const float* __restrict__ inp, const float* __restrict__ est_init,
    const u64* __restrict__ cbB, const u64* __restrict__ cbT,
    float* __restrict__ out) {
    __shared__ u64 s_hist[2][4][NF][NW];   // [row][ring4][factor][word], 8 KB
    __shared__ u64 s_inp[2][NW];
    __shared__ u64 s_ne[2][NF][NW];        // own-wave use only
    __shared__ int s_conv[2][NF];

    const int b    = blockIdx.x;           // 0..511
    const int tid  = threadIdx.x;
    const int j    = tid >> 6;             // wave = factor
    const int lane = tid & 63;
    const int rA   = b << 1;               // rows rA, rA+1

    const u64* cbBj = cbB + (j << 11);
    const u64* cbTj = cbT + (j << 11);

    // ---- pack input + est_0 for both rows ----
    #pragma unroll
    for (int r = 0; r < 2; ++r) {
        #pragma unroll
        for (int k = 0; k < 8; ++k) {
            const int w = (j << 3) + k;
            const u64 m = __ballot(inp[((rA + r) << 11) + (w << 6) + lane] < 0.0f);
            if (lane == 0) s_inp[r][w] = m;
        }
        #pragma unroll 4
        for (int w = 0; w < NW; ++w) {
            const u64 m = __ballot(
                est_init[((((rA + r) << 2) | j) << 11) + (w << 6) + lane] < 0.0f);
            if (lane == 0) s_hist[r][0][j][w] = m;
        }
    }
    __syncthreads();

    int mlA = 0, mpA = 0, fsA = 0;
    int mlB = 0, mpB = 0, fsB = 0;

    for (int it = 0; it < ITERS; ++it) {
        const int cur = it & 3, nxt = (it + 1) & 3, prv = (it + 3) & 3;

        // ne for own factor, both rows (own-wave LDS -> no barrier needed)
        if (lane < NW) {
            const u64 XA = s_inp[0][lane]
                ^ s_hist[0][cur][0][lane] ^ s_hist[0][cur][1][lane]
                ^ s_hist[0][cur][2][lane] ^ s_hist[0][cur][3][lane];
            s_ne[0][j][lane] = XA ^ s_hist[0][cur][j][lane];
            const u64 XB = s_inp[1][lane]
                ^ s_hist[1][cur][0][lane] ^ s_hist[1][cur][1][lane]
                ^ s_hist[1][cur][2][lane] ^ s_hist[1][cur][3][lane];
            s_ne[1][j][lane] = XB ^ s_hist[1][cur][j][lane];
        }

        // ---- phase B: pc_v both rows; each cbB word loaded once ----
        int pcA = 0, pcB = 0;
        #pragma unroll
        for (int ch = 0; ch < 8; ++ch) {
            const int w4 = ch << 2;
            const u64 g0 = cbBj[((w4 + 0) << 6) | lane];
            const u64 g1 = cbBj[((w4 + 1) << 6) | lane];
            const u64 g2 = cbBj[((w4 + 2) << 6) | lane];
            const u64 g3 = cbBj[((w4 + 3) << 6) | lane];
            pcA += (int)__popcll(s_ne[0][j][w4 + 0] ^ g0)
                 + (int)__popcll(s_ne[0][j][w4 + 1] ^ g1)
                 + (int)__popcll(s_ne[0][j][w4 + 2] ^ g2)
                 + (int)__popcll(s_ne[0][j][w4 + 3] ^ g3);
            pcB += (int)__popcll(s_ne[1][j][w4 + 0] ^ g0)
                 + (int)__popcll(s_ne[1][j][w4 + 1] ^ g1)
                 + (int)__popcll(s_ne[1][j][w4 + 2] ^ g2)
                 + (int)__popcll(s_ne[1][j][w4 + 3] ^ g3);
        }

        int mnA = pcA, spA = pcA, mnB = pcB, spB = pcB;
        #pragma unroll
        for (int off = 32; off > 0; off >>= 1) {
            const int a1 = __shfl_xor(mnA, off), a2 = __shfl_xor(spA, off);
            const int a3 = __shfl_xor(mnB, off), a4 = __shfl_xor(spB, off);
            mnA = mnA < a1 ? mnA : a1;  spA += a2;
            mnB = mnB < a3 ? mnB : a3;  spB += a4;
        }
        mpA = mlA; mlA = ND - 2 * mnA;
        mpB = mlB; mlB = ND - 2 * mnB;

        // ---- mean-centered exact decomposition, per row ----
        const int meanA = spA >> 6, devA = pcA - meanA;
        const int devcA = devA < -128 ? -128 : (devA > 127 ? 127 : devA);
        const int exA = devA - devcA, uA = devcA + 128;
        const int meanB = spB >> 6, devB = pcB - meanB;
        const int devcB = devB < -128 ? -128 : (devB > 127 ? 127 : devB);
        const int exB = devB - devcB, uB = devcB + 128;

        const u64 cA0 = __ballot(uA & 1),  cA1 = __ballot(uA & 2);
        const u64 cA2 = __ballot(uA & 4),  cA3 = __ballot(uA & 8);
        const u64 cA4 = __ballot(uA & 16), cA5 = __ballot(uA & 32);
        const u64 cA6 = __ballot(uA & 64), cA7 = __ballot(uA & 128);
        const u64 cB0 = __ballot(uB & 1),  cB1 = __ballot(uB & 2);
        const u64 cB2 = __ballot(uB & 4),  cB3 = __ballot(uB & 8);
        const u64 cB4 = __ballot(uB & 16), cB5 = __ballot(uB & 32);
        const u64 cB6 = __ballot(uB & 64), cB7 = __ballot(uB & 128);

        u64 omA = __ballot(exA != 0);
        const int novA = (int)__popcll(omA);
        int ovA0 = 0, ovA1 = 0, oeA0 = 0, oeA1 = 0;
        if (novA > 0) {
            ovA0 = __builtin_ctzll(omA); omA &= omA - 1;
            oeA0 = 4 * __builtin_amdgcn_readlane(exA, ovA0);
            if (novA > 1) {
                ovA1 = __builtin_ctzll(omA); omA &= omA - 1;
                oeA1 = 4 * __builtin_amdgcn_readlane(exA, ovA1);
            }
        }
        u64 omB = __ballot(exB != 0);
        const int novB = (int)__popcll(omB);
        int ovB0 = 0, ovB1 = 0, oeB0 = 0, oeB1 = 0;
        if (novB > 0) {
            ovB0 = __builtin_ctzll(omB); omB &= omB - 1;
            oeB0 = 4 * __builtin_amdgcn_readlane(exB, ovB0);
            if (novB > 1) {
                ovB1 = __builtin_ctzll(omB); omB &= omB - 1;
                oeB1 = 4 * __builtin_amdgcn_readlane(exB, ovB1);
            }
        }
        const int baseA = 131072 - 2 * spA, cmulA = 4 * meanA - 4608;
        const int baseB = 131072 - 2 * spB, cmulB = 4 * meanB - 4608;

        // ---- phase C: each cbT word loaded once, two rows computed ----
        #pragma unroll
        for (int ch = 0; ch < 8; ++ch) {
            const int w4 = ch << 2;
            const u64 ga = cbTj[((w4 + 0) << 6) | lane];
            const u64 gb = cbTj[((w4 + 1) << 6) | lane];
            const u64 gc = cbTj[((w4 + 2) << 6) | lane];
            const u64 gd = cbTj[((w4 + 3) << 6) | lane];
            #pragma unroll
            for (int k2 = 0; k2 < 4; ++k2) {
                const u64 cw = (k2 == 0) ? ga : (k2 == 1) ? gb
                             : (k2 == 2) ? gc : gd;
                const int colb = (int)__popcll(cw);
                int tA = baseA + cmulA * colb;
                tA += (int)__popcll(cA0 & cw) << 2;
                tA += (int)__popcll(cA1 & cw) << 3;
                tA += (int)__popcll(cA2 & cw) << 4;
                tA += (int)__popcll(cA3 & cw) << 5;
                tA += (int)__popcll(cA4 & cw) << 6;
                tA += (int)__popcll(cA5 & cw) << 7;
                tA += (int)__popcll(cA6 & cw) << 8;
                tA += (int)__popcll(cA7 & cw) << 9;
                tA += oeA0 * (int)((cw >> ovA0) & 1);
                tA += oeA1 * (int)((cw >> ovA1) & 1);
                if (novA > 2) {                    // exact, ~never taken
                    u64 m2 = omA;
                    while (m2) {
                        const int vv = __builtin_ctzll(m2); m2 &= m2 - 1;
                        tA += 4 * __builtin_amdgcn_readlane(exA, vv)
                                * (int)((cw >> vv) & 1);
                    }
                }
                int tB = baseB + cmulB * colb;
                tB += (int)__popcll(cB0 & cw) << 2;
                tB += (int)__popcll(cB1 & cw) << 3;
                tB += (int)__popcll(cB2 & cw) << 4;
                tB += (int)__popcll(cB3 & cw) << 5;
                tB += (int)__popcll(cB4 & cw) << 6;
                tB += (int)__popcll(cB5 & cw) << 7;
                tB += (int)__popcll(cB6 & cw) << 8;
                tB += (int)__popcll(cB7 & cw) << 9;
                tB += oeB0 * (int)((cw >> ovB0) & 1);
                tB += oeB1 * (int)((cw >> ovB1) & 1);
                if (novB > 2) {
                    u64 m2 = omB;
                    while (m2) {
                        const int vv = __builtin_ctzll(m2); m2 &= m2 - 1;
                        tB += 4 * __builtin_amdgcn_readlane(exB, vv)
                                * (int)((cw >> vv) & 1);
                    }
                }
                const u64 nwA = __ballot(tA < 0);
                const u64 nwB = __ballot(tB < 0);
                if (lane == 0) {
                    s_hist[0][nxt][j][w4 + k2] = nwA;
                    s_hist[1][nxt][j][w4 + k2] = nwB;
                }
            }
        }

        // ---- period<=2 check, both rows ----
        int d1A = 0, d2A = 0, d1B = 0, d2B = 0;
        if (lane < NW) {
            const u64 aA = s_hist[0][nxt][j][lane];
            d1A = (aA != s_hist[0][cur][j][lane]);
            d2A = (aA != s_hist[0][prv][j][lane]);
            const u64 aB = s_hist[1][nxt][j][lane];
            d1B = (aB != s_hist[1][cur][j][lane]);
            d2B = (aB != s_hist[1][prv][j][lane]);
        }
        const u64 bA1 = __ballot(d1A), bA2 = __ballot(d2A);
        const u64 bB1 = __ballot(d1B), bB2 = __ballot(d2B);
        if (lane == 0) {
            s_conv[0][j] = (bA1 == 0 ? 1 : 0) | (bA2 == 0 ? 2 : 0);
            s_conv[1][j] = (bB1 == 0 ? 1 : 0) | (bB2 == 0 ? 2 : 0);
        }
        __syncthreads();                          // the one barrier per iter

        const int flA = s_conv[0][0] & s_conv[0][1] & s_conv[0][2] & s_conv[0][3];
        const int flB = s_conv[1][0] & s_conv[1][1] & s_conv[1][2] & s_conv[1][3];
        fsA = nxt; fsB = nxt;
        const bool okA = (flA & 1) || (it >= 1 && (flA & 2));
        const bool okB = (flB & 1) || (it >= 1 && (flB & 2));
        if (okA && okB) {
            if (!(flA & 1) && ((ITERS - it) & 1) == 0) { fsA = cur; mlA = mpA; }
            if (!(flB & 1) && ((ITERS - it) & 1) == 0) { fsB = cur; mlB = mpB; }
            break;
        }
    }

    // ---- epilogue per row: outcome + max_sim + unpack ----
    #pragma unroll
    for (int r = 0; r < 2; ++r) {
        const int fs = r ? fsB : fsA;
        const int ml = r ? mlB : mlA;
        int pcO = 0;
        #pragma unroll
        for (int w = 0; w < NW; ++w)
            pcO += (int)__popcll(s_hist[r][fs][j][w] ^ cbBj[(w << 6) | lane]);
        const int simF = ND - (pcO << 1);
        const int aF   = simF < 0 ? -simF : simF;
        int key = (aF << 6) | (63 - lane);
        #pragma unroll
        for (int off = 32; off > 0; off >>= 1) {
            const int t1 = __shfl_xor(key, off);
            key = key > t1 ? key : t1;
        }
        if (lane == 0) {
            out[OFF_OUT + ((rA + r) << 2) + j] = (float)(63 - (key & 63));
            out[OFF_MS  + ((rA + r) << 2) + j] = (float)ml;
        }
        #pragma unroll 4
        for (int k = 0; k < 32; ++k) {
            const int idx = tid + (k << 8);        // 0..8191
            const int jj = idx >> 11, d = idx & 2047;
            const u64 wrd = s_hist[r][fs][jj][d >> 6];
            out[((rA + r) << 13) + idx] = ((wrd >> (d & 63)) & 1) ? -1.0f : 1.0f;
        }
    }
    if (b == 0 && tid == 0) out[OFF_CONV] = 99.0f;
}

extern "C" void kernel_launch(void* const* d_in, const int* in_sizes, int n_in,
                              void* d_out, int out_size, void* d_ws, size_t ws_size,
                              hipStream_t stream) {
    const float* inp  = (const float*)d_in[0];
    const float* est0 = (const float*)d_in[1];
    const float* cb   = (const float*)d_in[2];
    float* out = (float*)d_out;
    u64* cbB = (u64*)d_ws;                 // 8192 words
    u64* cbT = cbB + NF * 64 * NW;         // 8192 words (128 KB of ws total)

    pack_cb_kernel<<<64, 256, 0, stream>>>(cb, cbB, cbT);
    resonator_kernel<<<NB / 2, 256, 0, stream>>>(inp, est0, cbB, cbT, out);
}